// Round 1
// baseline (1634.702 us; speedup 1.0000x reference)
//
#include <hip/hip_runtime.h>

#define N_NODES 20000
#define N_EDGES 320000
#define X_DIM 128
#define EDGE_DIM 64
#define HIDDEN 256
#define N_GRAPHS 64
#define LAYERS 3

#define NPB 8    // nodes per block (node_proj)
#define EPB 16   // edges per block (edge_msg)
#define RPB 16   // rows per block (mlp)

// h[i] = x[i] @ xW + xb ; also zero agg for layer 0
__global__ __launch_bounds__(256) void node_proj_kernel(
    const float* __restrict__ x, const float* __restrict__ W,
    const float* __restrict__ b, float* __restrict__ h, float* __restrict__ agg)
{
    const int t = threadIdx.x;
    const int row0 = blockIdx.x * NPB;
    __shared__ float xs[NPB][X_DIM];
    for (int idx = t; idx < NPB * X_DIM; idx += 256)
        xs[idx / X_DIM][idx % X_DIM] = x[(size_t)row0 * X_DIM + idx];
    __syncthreads();
    float acc[NPB];
    const float bt = b[t];
#pragma unroll
    for (int r = 0; r < NPB; r++) acc[r] = bt;
    for (int k = 0; k < X_DIM; k++) {
        const float wv = W[k * HIDDEN + t];
#pragma unroll
        for (int r = 0; r < NPB; r++) acc[r] += xs[r][k] * wv;
    }
#pragma unroll
    for (int r = 0; r < NPB; r++) {
        h[(size_t)(row0 + r) * HIDDEN + t] = acc[r];
        agg[(size_t)(row0 + r) * HIDDEN + t] = 0.f;
    }
}

// msg = relu(h[src] + edge_attr @ eW + eb); atomicAdd into agg[dst]
__global__ __launch_bounds__(256) void edge_msg_kernel(
    const float* __restrict__ ea, const int* __restrict__ ei,
    const float* __restrict__ W, const float* __restrict__ b,
    const float* __restrict__ h, float* __restrict__ agg)
{
    const int t = threadIdx.x;
    const int e0 = blockIdx.x * EPB;
    __shared__ float es[EPB][EDGE_DIM];
    __shared__ int s_src[EPB], s_dst[EPB];
    for (int idx = t; idx < EPB * EDGE_DIM; idx += 256)
        es[idx / EDGE_DIM][idx % EDGE_DIM] = ea[(size_t)e0 * EDGE_DIM + idx];
    if (t < EPB) {
        s_src[t] = ei[e0 + t];
        s_dst[t] = ei[N_EDGES + e0 + t];
    }
    __syncthreads();
    float acc[EPB];
    const float bt = b[t];
#pragma unroll
    for (int e = 0; e < EPB; e++) acc[e] = bt;
    for (int k = 0; k < EDGE_DIM; k++) {
        const float wv = W[k * HIDDEN + t];
#pragma unroll
        for (int e = 0; e < EPB; e++) acc[e] += es[e][k] * wv;
    }
#pragma unroll
    for (int e = 0; e < EPB; e++) {
        float v = h[(size_t)s_src[e] * HIDDEN + t] + acc[e];
        v = v > 0.f ? v : 0.f;
        atomicAdd(&agg[(size_t)s_dst[e] * HIDDEN + t], v);
    }
}

// z = h + agg; h = relu(relu(z@W1+b1)@W2+b2); zero agg for next layer
__global__ __launch_bounds__(256) void mlp_kernel(
    const float* __restrict__ W1, const float* __restrict__ b1,
    const float* __restrict__ W2, const float* __restrict__ b2,
    float* __restrict__ h, float* __restrict__ agg)
{
    const int t = threadIdx.x;
    const int row0 = blockIdx.x * RPB;
    __shared__ float zs[RPB][HIDDEN];
    __shared__ float ts[RPB][HIDDEN];
#pragma unroll
    for (int r = 0; r < RPB; r++) {
        const size_t idx = (size_t)(row0 + r) * HIDDEN + t;
        zs[r][t] = h[idx] + agg[idx];
        agg[idx] = 0.f;
    }
    __syncthreads();
    float acc[RPB];
    const float bt1 = b1[t];
#pragma unroll
    for (int r = 0; r < RPB; r++) acc[r] = bt1;
    for (int k = 0; k < HIDDEN; k++) {
        const float wv = W1[k * HIDDEN + t];
#pragma unroll
        for (int r = 0; r < RPB; r++) acc[r] += zs[r][k] * wv;
    }
    __syncthreads();
#pragma unroll
    for (int r = 0; r < RPB; r++) ts[r][t] = acc[r] > 0.f ? acc[r] : 0.f;
    __syncthreads();
    const float bt2 = b2[t];
#pragma unroll
    for (int r = 0; r < RPB; r++) acc[r] = bt2;
    for (int k = 0; k < HIDDEN; k++) {
        const float wv = W2[k * HIDDEN + t];
#pragma unroll
        for (int r = 0; r < RPB; r++) acc[r] += ts[r][k] * wv;
    }
#pragma unroll
    for (int r = 0; r < RPB; r++) {
        const float v = acc[r];
        h[(size_t)(row0 + r) * HIDDEN + t] = v > 0.f ? v : 0.f;
    }
}

// mean pool per graph; batch_ids is sorted -> binary search segment bounds
__global__ __launch_bounds__(256) void pool_kernel(
    const float* __restrict__ h, const int* __restrict__ bid,
    float* __restrict__ gout)
{
    const int g = blockIdx.x;
    const int t = threadIdx.x;
    int lo = 0, hi = N_NODES;
    while (lo < hi) { int mid = (lo + hi) >> 1; if (bid[mid] < g) lo = mid + 1; else hi = mid; }
    const int start = lo;
    hi = N_NODES;
    while (lo < hi) { int mid = (lo + hi) >> 1; if (bid[mid] < g + 1) lo = mid + 1; else hi = mid; }
    const int end = lo;
    float s = 0.f;
    for (int i = start; i < end; i++) s += h[(size_t)i * HIDDEN + t];
    const float cnt = (float)(end - start);
    gout[g * HIDDEN + t] = s / (cnt > 1.f ? cnt : 1.f);
}

// out = normalize(relu(g@oW1+ob1)@oW2+ob2)
__global__ __launch_bounds__(256) void head_kernel(
    const float* __restrict__ gin, const float* __restrict__ W1,
    const float* __restrict__ b1, const float* __restrict__ W2,
    const float* __restrict__ b2, float* __restrict__ out)
{
    const int g = blockIdx.x;
    const int t = threadIdx.x;
    __shared__ float gs[HIDDEN];
    __shared__ float t1[HIDDEN];
    __shared__ float red[256];
    gs[t] = gin[g * HIDDEN + t];
    __syncthreads();
    float acc = b1[t];
    for (int k = 0; k < HIDDEN; k++) acc += gs[k] * W1[k * HIDDEN + t];
    t1[t] = acc > 0.f ? acc : 0.f;
    __syncthreads();
    float acc2 = b2[t];
    for (int k = 0; k < HIDDEN; k++) acc2 += t1[k] * W2[k * HIDDEN + t];
    red[t] = acc2 * acc2;
    __syncthreads();
    for (int s = 128; s > 0; s >>= 1) {
        if (t < s) red[t] += red[t + s];
        __syncthreads();
    }
    float norm = sqrtf(red[0]);
    norm = norm > 1e-12f ? norm : 1e-12f;
    out[g * HIDDEN + t] = acc2 / norm;
}

extern "C" void kernel_launch(void* const* d_in, const int* in_sizes, int n_in,
                              void* d_out, int out_size, void* d_ws, size_t ws_size,
                              hipStream_t stream)
{
    const float* x   = (const float*)d_in[0];
    const int*   ei  = (const int*)d_in[1];
    const float* ea  = (const float*)d_in[2];
    const int*   bid = (const int*)d_in[3];
    const float* xW  = (const float*)d_in[4];
    const float* xb  = (const float*)d_in[5];
    const float* eW  = (const float*)d_in[6];
    const float* eb  = (const float*)d_in[7];
    const float* W1  = (const float*)d_in[8];
    const float* b1  = (const float*)d_in[9];
    const float* W2  = (const float*)d_in[10];
    const float* b2  = (const float*)d_in[11];
    const float* oW1 = (const float*)d_in[12];
    const float* ob1 = (const float*)d_in[13];
    const float* oW2 = (const float*)d_in[14];
    const float* ob2 = (const float*)d_in[15];
    float* out = (float*)d_out;

    float* h     = (float*)d_ws;
    float* agg   = h + (size_t)N_NODES * HIDDEN;
    float* gpool = agg + (size_t)N_NODES * HIDDEN;

    node_proj_kernel<<<N_NODES / NPB, 256, 0, stream>>>(x, xW, xb, h, agg);
    for (int l = 0; l < LAYERS; l++) {
        edge_msg_kernel<<<N_EDGES / EPB, 256, 0, stream>>>(
            ea, ei, eW + (size_t)l * EDGE_DIM * HIDDEN, eb + l * HIDDEN, h, agg);
        mlp_kernel<<<N_NODES / RPB, 256, 0, stream>>>(
            W1 + (size_t)l * HIDDEN * HIDDEN, b1 + l * HIDDEN,
            W2 + (size_t)l * HIDDEN * HIDDEN, b2 + l * HIDDEN, h, agg);
    }
    pool_kernel<<<N_GRAPHS, 256, 0, stream>>>(h, bid, gpool);
    head_kernel<<<N_GRAPHS, 256, 0, stream>>>(gpool, oW1, ob1, oW2, ob2, out);
}